// Round 6
// baseline (83.897 us; speedup 1.0000x reference)
//
#include <hip/hip_runtime.h>
#include <math.h>

// Triangle-triangle intersection, bit-exact vs the numpy/JAX reference.
//  - EPS snap at 1e-6, reference op order, fp contract OFF, IEEE divides.
//  - R6: back to the barrier-free streaming structure (R1 ran at ~85% issue
//    efficiency; every LDS/barrier-tiled variant R3-R5 ran at ~40%). Redundant
//    work removed instead: triu-only compute + scattered mirror dword, planes
//    precomputed, wave-uniform row triangle via readfirstlane -> s_load.

static constexpr float EPS_SNAP = 1e-6f;

__device__ __forceinline__ float snapz(float x) {
    return (fabsf(x) < EPS_SNAP) ? 0.0f : x;
}

// Interval of the intersection line covered by one triangle (reference order).
__device__ __forceinline__ void tri_interval(const float p[3], const float d[3],
                                             float& tmin, float& tmax) {
#pragma clang fp contract(off)
    tmin = INFINITY;
    tmax = -INFINITY;
#pragma unroll
    for (int e = 0; e < 3; ++e) {
        const int i0 = e;
        const int i1 = (e + 1) % 3;  // edges (0,1),(1,2),(2,0)
        const float di = d[i0], dj = d[i1];
        const float pi = p[i0], pj = p[i1];
        const bool valid = (di * dj <= 0.0f) && !((di == 0.0f) && (dj == 0.0f));
        const float denom = di - dj;
        const float dsafe = (denom == 0.0f) ? 1.0f : denom;
        const float t = pi + ((pj - pi) * di) / dsafe;  // ((pj-pi)*di)/denom
        if (valid) {
            tmin = fminf(tmin, t);
            tmax = fmaxf(tmax, t);
        }
    }
}

// Pre-pass: per-triangle plane normal + offset (reference arithmetic order).
__global__ __launch_bounds__(256) void plane_kernel(
    const float* __restrict__ tri, float4* __restrict__ planes, int n)
{
#pragma clang fp contract(off)
    const int i = blockIdx.x * 256 + threadIdx.x;
    if (i >= n) return;
    const float* A = tri + (size_t)i * 9;
    float Av[9];
#pragma unroll
    for (int k = 0; k < 9; ++k) Av[k] = A[k];
    const float e1x = Av[3] - Av[0], e1y = Av[4] - Av[1], e1z = Av[5] - Av[2];
    const float e2x = Av[6] - Av[0], e2y = Av[7] - Av[1], e2z = Av[8] - Av[2];
    const float nx = e1y * e2z - e1z * e2y;
    const float ny = e1z * e2x - e1x * e2z;
    const float nz = e1x * e2y - e1y * e2x;
    const float d = -(((nx * Av[0]) + (ny * Av[1])) + (nz * Av[2]));
    planes[i] = make_float4(nx, ny, nz, d);
}

// Streaming pair kernel: block (64,4) -> one output row per wave; thread owns
// pair (i,j) with i<j, writes both cells. No LDS, no __syncthreads.
__global__ __launch_bounds__(256, 4) void pair_kernel(
    const float* __restrict__ tri, const float4* __restrict__ planes,
    float* __restrict__ out, int n)
{
#pragma clang fp contract(off)
    const int j = blockIdx.x * 64 + threadIdx.x;  // column
    const int i = blockIdx.y * 4 + threadIdx.y;   // row (wave-uniform)
    if (i > j) return;  // lower half owned by mirror; also kills dead tiles
    if (i == j) { out[(size_t)i * n + j] = 1.0f; return; }

    // Row triangle + plane: wave-uniform -> scalar loads (s_load).
    const int iu = __builtin_amdgcn_readfirstlane(i);
    const float* __restrict__ A = tri + (size_t)iu * 9;
    float Av[9];
#pragma unroll
    for (int k = 0; k < 9; ++k) Av[k] = A[k];
    const float4 pa = planes[iu];
    const float nax = pa.x, nay = pa.y, naz = pa.z, da = pa.w;

    // Column triangle + plane: per-lane.
    const float* __restrict__ B = tri + (size_t)j * 9;
    float Bv[9];
#pragma unroll
    for (int k = 0; k < 9; ++k) Bv[k] = B[k];
    const float4 pb = planes[j];
    const float nbx = pb.x, nby = pb.y, nbz = pb.z, db = pb.w;

    // Signed distances (left-to-right 3-term dot + offset, then snap).
    float dv[3], du[3];
#pragma unroll
    for (int v = 0; v < 3; ++v) {
        dv[v] = snapz((((Av[3 * v] * nbx) + (Av[3 * v + 1] * nby)) + (Av[3 * v + 2] * nbz)) + db);
        du[v] = snapz((((Bv[3 * v] * nax) + (Bv[3 * v + 1] * nay)) + (Bv[3 * v + 2] * naz)) + da);
    }

    const bool ssv = (dv[0] > 0.0f && dv[1] > 0.0f && dv[2] > 0.0f) ||
                     (dv[0] < 0.0f && dv[1] < 0.0f && dv[2] < 0.0f);
    const bool ssu = (du[0] > 0.0f && du[1] > 0.0f && du[2] > 0.0f) ||
                     (du[0] < 0.0f && du[1] < 0.0f && du[2] < 0.0f);

    // Plane-plane line direction, dominant axis (first-occurrence argmax).
    const float Dx = nay * nbz - naz * nby;
    const float Dy = naz * nbx - nax * nbz;
    const float Dz = nax * nby - nay * nbx;
    const float m0 = fabsf(Dx), m1 = fabsf(Dy), m2 = fabsf(Dz);
    int axm = 0;
    float mm = m0;
    if (m1 > mm) { axm = 1; mm = m1; }
    if (m2 > mm) { axm = 2; }

    float pv[3], pu[3];
#pragma unroll
    for (int v = 0; v < 3; ++v) {
        pv[v] = (axm == 0) ? Av[3 * v] : ((axm == 1) ? Av[3 * v + 1] : Av[3 * v + 2]);
        pu[v] = (axm == 0) ? Bv[3 * v] : ((axm == 1) ? Bv[3 * v + 1] : Bv[3 * v + 2]);
    }

    float t0v, t1v, t0u, t1u;
    tri_interval(pv, dv, t0v, t1v);
    tri_interval(pu, du, t0u, t1u);

    const bool overlap = fmaxf(t0v, t0u) <= fminf(t1v, t1u);
    const bool hit = (!ssv) && (!ssu) && overlap;
    const float res = hit ? 1.0f : 0.0f;

    out[(size_t)i * n + j] = res;  // coalesced (wave = 64 consecutive j)
    out[(size_t)j * n + i] = res;  // scattered mirror dword (fire-and-forget)
}

extern "C" void kernel_launch(void* const* d_in, const int* in_sizes, int n_in,
                              void* d_out, int out_size, void* d_ws, size_t ws_size,
                              hipStream_t stream) {
    const float* tri = (const float*)d_in[0];
    float* out = (float*)d_out;
    const int n = in_sizes[0] / 9;  // 2048
    float4* planes = (float4*)d_ws;

    plane_kernel<<<(n + 255) / 256, 256, 0, stream>>>(tri, planes, n);

    dim3 block(64, 4);
    dim3 grid((n + 63) / 64, (n + 3) / 4);  // tiles fully below diag exit fast
    pair_kernel<<<grid, block, 0, stream>>>(tri, planes, out, n);
}

// Round 7
// 71.564 us; speedup vs baseline: 1.1723x; 1.1723x over previous
//
#include <hip/hip_runtime.h>
#include <math.h>

// Triangle-triangle intersection, bit-exact vs the numpy/JAX reference.
//  - EPS snap at 1e-6, reference op order, fp contract OFF, IEEE divides.
//  - Structure: R5's triu 32x32 tiles + survivor compaction (best measured).
//  - R7 changes: raw-min/max straddle gate (no per-element snap in phase 1),
//    phase-1 writes the result tile directly (no zero-init pass), planes
//    computed concurrently with staging (3 barriers instead of 4),
//    launch_bounds(256,6) for more resident waves to hide divide latency.

static constexpr float EPS_SNAP = 1e-6f;
static constexpr int TS = 32;  // tile size; n=2048 divisible

__device__ __forceinline__ float snapz(float x) {
    return (fabsf(x) < EPS_SNAP) ? 0.0f : x;
}

// Interval of the intersection line covered by one triangle (reference order).
__device__ __forceinline__ void tri_interval(const float p[3], const float d[3],
                                             float& tmin, float& tmax) {
#pragma clang fp contract(off)
    tmin = INFINITY;
    tmax = -INFINITY;
#pragma unroll
    for (int e = 0; e < 3; ++e) {
        const int i0 = e;
        const int i1 = (e + 1) % 3;  // edges (0,1),(1,2),(2,0)
        const float di = d[i0], dj = d[i1];
        const float pi = p[i0], pj = p[i1];
        const bool valid = (di * dj <= 0.0f) && !((di == 0.0f) && (dj == 0.0f));
        const float denom = di - dj;
        const float dsafe = (denom == 0.0f) ? 1.0f : denom;
        const float t = pi + ((pj - pi) * di) / dsafe;  // ((pj-pi)*di)/denom
        if (valid) {
            tmin = fminf(tmin, t);
            tmax = fmaxf(tmax, t);
        }
    }
}

__global__ __launch_bounds__(256, 6) void tile_kernel(
    const float* __restrict__ tri, float* __restrict__ out, int n)
{
#pragma clang fp contract(off)
    const int nt = n / TS;  // 64
    // Linear id -> (tr, tc), tr <= tc (cheap scalar loop, ~nt iterations).
    int k = blockIdx.x, tr = 0;
    while (k >= nt - tr) { k -= nt - tr; ++tr; }
    const int tc = tr + k;
    const int R = tr * TS, C = tc * TS;

    __shared__ float Asf[TS * 12];            // row tris, padded to 12 floats
    __shared__ float Bsf[TS * 12];            // col tris
    __shared__ float4 Apl[TS], Bpl[TS];       // planes (normal, offset)
    __shared__ float Sres[TS][TS + 1];        // result tile
    __shared__ unsigned short qbuf[TS * TS];  // survivor queue (r<<5|c)
    __shared__ int s_cnt;

    const int tx = threadIdx.x;  // 0..31 column in tile
    const int ty = threadIdx.y;  // 0..7
    const int t = ty * TS + tx;  // 0..255
    const int lane = t & 63;

    // ---- stage verts (coalesced dwords -> padded LDS rows) ----
    if (t == 0) s_cnt = 0;
    for (int g = t; g < TS * 9; g += 256) {
        const int a = g / 9, c9 = g - a * 9;
        Asf[a * 12 + c9] = tri[(size_t)R * 9 + g];
        Bsf[a * 12 + c9] = tri[(size_t)C * 9 + g];
    }
    // ---- planes from global, concurrent with staging (threads 0..63) ----
    if (t < 2 * TS) {
        const int idx = (t < TS) ? (R + t) : (C + (t - TS));
        const float* V = tri + (size_t)idx * 9;
        float Vv[9];
#pragma unroll
        for (int q = 0; q < 9; ++q) Vv[q] = V[q];
        const float e1x = Vv[3] - Vv[0], e1y = Vv[4] - Vv[1], e1z = Vv[5] - Vv[2];
        const float e2x = Vv[6] - Vv[0], e2y = Vv[7] - Vv[1], e2z = Vv[8] - Vv[2];
        const float nx = e1y * e2z - e1z * e2y;
        const float ny = e1z * e2x - e1x * e2z;
        const float nz = e1x * e2y - e1y * e2x;
        const float d = -(((nx * Vv[0]) + (ny * Vv[1])) + (nz * Vv[2]));
        if (t < TS) Apl[t] = make_float4(nx, ny, nz, d);
        else        Bpl[t - TS] = make_float4(nx, ny, nz, d);
    }
    __syncthreads();

    // ---- phase 1: raw-distance straddle gate, write 0/1, compact survivors --
    // all(snap(d)>0) <=> min(raw) >= EPS ; all(snap(d)<0) <=> max(raw) <= -EPS
    float Bv[9];
    {
        const float4 b0 = *(const float4*)&Bsf[tx * 12];
        const float4 b1 = *(const float4*)&Bsf[tx * 12 + 4];
        Bv[0] = b0.x; Bv[1] = b0.y; Bv[2] = b0.z; Bv[3] = b0.w;
        Bv[4] = b1.x; Bv[5] = b1.y; Bv[6] = b1.z; Bv[7] = b1.w;
        Bv[8] = Bsf[tx * 12 + 8];
    }
    const float4 pb = Bpl[tx];

    for (int kk = 0; kk < 4; ++kk) {
        const int r = ty + 8 * kk;
        const float4 a0 = *(const float4*)&Asf[r * 12];
        const float4 a1 = *(const float4*)&Asf[r * 12 + 4];
        const float a8 = Asf[r * 12 + 8];
        const float4 pa = Apl[r];
        // raw signed distances (left-to-right dot + offset, ref order)
        const float dv0 = (((a0.x * pb.x) + (a0.y * pb.y)) + (a0.z * pb.z)) + pb.w;
        const float dv1 = (((a0.w * pb.x) + (a1.x * pb.y)) + (a1.y * pb.z)) + pb.w;
        const float dv2 = (((a1.z * pb.x) + (a1.w * pb.y)) + (a8 * pb.z)) + pb.w;
        const float du0 = (((Bv[0] * pa.x) + (Bv[1] * pa.y)) + (Bv[2] * pa.z)) + pa.w;
        const float du1 = (((Bv[3] * pa.x) + (Bv[4] * pa.y)) + (Bv[5] * pa.z)) + pa.w;
        const float du2 = (((Bv[6] * pa.x) + (Bv[7] * pa.y)) + (Bv[8] * pa.z)) + pa.w;
        const float mnv = fminf(fminf(dv0, dv1), dv2), mxv = fmaxf(fmaxf(dv0, dv1), dv2);
        const float mnu = fminf(fminf(du0, du1), du2), mxu = fmaxf(fmaxf(du0, du1), du2);
        const bool ssv = (mnv >= EPS_SNAP) || (mxv <= -EPS_SNAP);
        const bool ssu = (mnu >= EPS_SNAP) || (mxu <= -EPS_SNAP);
        const int i = R + r, j = C + tx;
        const bool surv = !ssv && !ssu && (i != j);
        Sres[r][tx] = (i == j) ? 1.0f : 0.0f;  // survivors overwritten in phase 2
        // wave-aggregated enqueue
        const unsigned long long m = __ballot(surv);
        int wb = 0;
        if (lane == 0) {
            const int wcnt = __popcll(m);
            if (wcnt) wb = atomicAdd(&s_cnt, wcnt);
        }
        wb = __shfl(wb, 0);
        if (surv) {
            const int pos = wb + __popcll(m & ((1ull << lane) - 1ull));
            qbuf[pos] = (unsigned short)((r << 5) | tx);
        }
    }
    __syncthreads();

    // ---- phase 2: full interval test on survivors only ----
    const int total = s_cnt;
    for (int q = t; q < total; q += 256) {
        const int e = qbuf[q];
        const int r = e >> 5, c = e & 31;

        float Av[9], Bw[9];
        {
            const float4 a0 = *(const float4*)&Asf[r * 12];
            const float4 a1 = *(const float4*)&Asf[r * 12 + 4];
            Av[0] = a0.x; Av[1] = a0.y; Av[2] = a0.z; Av[3] = a0.w;
            Av[4] = a1.x; Av[5] = a1.y; Av[6] = a1.z; Av[7] = a1.w;
            Av[8] = Asf[r * 12 + 8];
            const float4 b0 = *(const float4*)&Bsf[c * 12];
            const float4 b1 = *(const float4*)&Bsf[c * 12 + 4];
            Bw[0] = b0.x; Bw[1] = b0.y; Bw[2] = b0.z; Bw[3] = b0.w;
            Bw[4] = b1.x; Bw[5] = b1.y; Bw[6] = b1.z; Bw[7] = b1.w;
            Bw[8] = Bsf[c * 12 + 8];
        }
        const float4 pa = Apl[r];
        const float4 pq = Bpl[c];
        const float nax = pa.x, nay = pa.y, naz = pa.z, da = pa.w;
        const float nbx = pq.x, nby = pq.y, nbz = pq.z, db = pq.w;

        // snapped distances (reference order + snap)
        float dv[3], du[3];
#pragma unroll
        for (int v = 0; v < 3; ++v) {
            dv[v] = snapz((((Av[3 * v] * nbx) + (Av[3 * v + 1] * nby)) + (Av[3 * v + 2] * nbz)) + db);
            du[v] = snapz((((Bw[3 * v] * nax) + (Bw[3 * v + 1] * nay)) + (Bw[3 * v + 2] * naz)) + da);
        }

        // plane-plane line direction, dominant axis (first-occurrence argmax)
        const float Dx = nay * nbz - naz * nby;
        const float Dy = naz * nbx - nax * nbz;
        const float Dz = nax * nby - nay * nbx;
        const float m0 = fabsf(Dx), m1 = fabsf(Dy), m2 = fabsf(Dz);
        int axm = 0;
        float mm = m0;
        if (m1 > mm) { axm = 1; mm = m1; }
        if (m2 > mm) { axm = 2; }

        float pv[3], pu[3];
#pragma unroll
        for (int v = 0; v < 3; ++v) {
            pv[v] = (axm == 0) ? Av[3 * v] : ((axm == 1) ? Av[3 * v + 1] : Av[3 * v + 2]);
            pu[v] = (axm == 0) ? Bw[3 * v] : ((axm == 1) ? Bw[3 * v + 1] : Bw[3 * v + 2]);
        }

        float t0v, t1v, t0u, t1u;
        tri_interval(pv, dv, t0v, t1v);
        tri_interval(pu, du, t0u, t1u);

        const bool overlap = fmaxf(t0v, t0u) <= fminf(t1v, t1u);
        Sres[r][c] = overlap ? 1.0f : 0.0f;  // queued => ~ssv & ~ssu already
    }
    __syncthreads();

    // ---- write out tile (+ mirror), coalesced float4 ----
    {
        const int row = t >> 3;          // 0..31
        const int c4 = (t & 7) * 4;      // 0,4,...,28
        float4 v;
        v.x = Sres[row][c4 + 0]; v.y = Sres[row][c4 + 1];
        v.z = Sres[row][c4 + 2]; v.w = Sres[row][c4 + 3];
        *(float4*)&out[(size_t)(R + row) * n + C + c4] = v;
        if (tr != tc) {
            float4 w;
            w.x = Sres[c4 + 0][row]; w.y = Sres[c4 + 1][row];
            w.z = Sres[c4 + 2][row]; w.w = Sres[c4 + 3][row];
            *(float4*)&out[(size_t)(C + row) * n + R + c4] = w;
        }
    }
}

extern "C" void kernel_launch(void* const* d_in, const int* in_sizes, int n_in,
                              void* d_out, int out_size, void* d_ws, size_t ws_size,
                              hipStream_t stream) {
    const float* tri = (const float*)d_in[0];
    float* out = (float*)d_out;
    const int n = in_sizes[0] / 9;  // 2048

    const int nt = n / TS;                   // 64
    const int nblocks = nt * (nt + 1) / 2;   // 2080 triu tiles
    dim3 block(TS, 8);
    tile_kernel<<<nblocks, block, 0, stream>>>(tri, out, n);
}

// Round 8
// 71.201 us; speedup vs baseline: 1.1783x; 1.0051x over previous
//
#include <hip/hip_runtime.h>
#include <math.h>

// Triangle-triangle intersection, bit-exact vs the numpy/JAX reference.
//  - EPS snap at 1e-6, reference op order, fp contract OFF, IEEE divides.
//  - Structure: R5/R7 triu 32x32 tiles + survivor compaction (best measured).
//  - R8 changes: launch_bounds(256,8) -> 32 waves/CU (hardware max) to hide
//    the serial IEEE-divide macro chains; phase-2 projections read straight
//    from LDS by index (bitwise-identical, kills the Av/Bw register liveness
//    across the divide section so 64 VGPRs suffice).

static constexpr float EPS_SNAP = 1e-6f;
static constexpr int TS = 32;  // tile size; n=2048 divisible

__device__ __forceinline__ float snapz(float x) {
    return (fabsf(x) < EPS_SNAP) ? 0.0f : x;
}

// Interval of the intersection line covered by one triangle (reference order).
__device__ __forceinline__ void tri_interval(const float p[3], const float d[3],
                                             float& tmin, float& tmax) {
#pragma clang fp contract(off)
    tmin = INFINITY;
    tmax = -INFINITY;
#pragma unroll
    for (int e = 0; e < 3; ++e) {
        const int i0 = e;
        const int i1 = (e + 1) % 3;  // edges (0,1),(1,2),(2,0)
        const float di = d[i0], dj = d[i1];
        const float pi = p[i0], pj = p[i1];
        const bool valid = (di * dj <= 0.0f) && !((di == 0.0f) && (dj == 0.0f));
        const float denom = di - dj;
        const float dsafe = (denom == 0.0f) ? 1.0f : denom;
        const float t = pi + ((pj - pi) * di) / dsafe;  // ((pj-pi)*di)/denom
        if (valid) {
            tmin = fminf(tmin, t);
            tmax = fmaxf(tmax, t);
        }
    }
}

__global__ __launch_bounds__(256, 8) void tile_kernel(
    const float* __restrict__ tri, float* __restrict__ out, int n)
{
#pragma clang fp contract(off)
    const int nt = n / TS;  // 64
    // Linear id -> (tr, tc), tr <= tc (cheap scalar loop).
    int k = blockIdx.x, tr = 0;
    while (k >= nt - tr) { k -= nt - tr; ++tr; }
    const int tc = tr + k;
    const int R = tr * TS, C = tc * TS;

    __shared__ float Asf[TS * 12];            // row tris, padded to 12 floats
    __shared__ float Bsf[TS * 12];            // col tris
    __shared__ float4 Apl[TS], Bpl[TS];       // planes (normal, offset)
    __shared__ float Sres[TS][TS + 1];        // result tile
    __shared__ unsigned short qbuf[TS * TS];  // survivor queue (r<<5|c)
    __shared__ int s_cnt;

    const int tx = threadIdx.x;  // 0..31 column in tile
    const int ty = threadIdx.y;  // 0..7
    const int t = ty * TS + tx;  // 0..255
    const int lane = t & 63;

    // ---- stage verts (coalesced dwords -> padded LDS rows) ----
    if (t == 0) s_cnt = 0;
    for (int g = t; g < TS * 9; g += 256) {
        const int a = g / 9, c9 = g - a * 9;
        Asf[a * 12 + c9] = tri[(size_t)R * 9 + g];
        Bsf[a * 12 + c9] = tri[(size_t)C * 9 + g];
    }
    // ---- planes from global, concurrent with staging (threads 0..63) ----
    if (t < 2 * TS) {
        const int idx = (t < TS) ? (R + t) : (C + (t - TS));
        const float* V = tri + (size_t)idx * 9;
        float Vv[9];
#pragma unroll
        for (int q = 0; q < 9; ++q) Vv[q] = V[q];
        const float e1x = Vv[3] - Vv[0], e1y = Vv[4] - Vv[1], e1z = Vv[5] - Vv[2];
        const float e2x = Vv[6] - Vv[0], e2y = Vv[7] - Vv[1], e2z = Vv[8] - Vv[2];
        const float nx = e1y * e2z - e1z * e2y;
        const float ny = e1z * e2x - e1x * e2z;
        const float nz = e1x * e2y - e1y * e2x;
        const float d = -(((nx * Vv[0]) + (ny * Vv[1])) + (nz * Vv[2]));
        if (t < TS) Apl[t] = make_float4(nx, ny, nz, d);
        else        Bpl[t - TS] = make_float4(nx, ny, nz, d);
    }
    __syncthreads();

    // ---- phase 1: raw-distance straddle gate, write 0/1, compact survivors --
    // all(snap(d)>0) <=> min(raw) >= EPS ; all(snap(d)<0) <=> max(raw) <= -EPS
    float Bv[9];
    {
        const float4 b0 = *(const float4*)&Bsf[tx * 12];
        const float4 b1 = *(const float4*)&Bsf[tx * 12 + 4];
        Bv[0] = b0.x; Bv[1] = b0.y; Bv[2] = b0.z; Bv[3] = b0.w;
        Bv[4] = b1.x; Bv[5] = b1.y; Bv[6] = b1.z; Bv[7] = b1.w;
        Bv[8] = Bsf[tx * 12 + 8];
    }
    const float4 pb = Bpl[tx];

    for (int kk = 0; kk < 4; ++kk) {
        const int r = ty + 8 * kk;
        const float4 a0 = *(const float4*)&Asf[r * 12];
        const float4 a1 = *(const float4*)&Asf[r * 12 + 4];
        const float a8 = Asf[r * 12 + 8];
        const float4 pa = Apl[r];
        // raw signed distances (left-to-right dot + offset, ref order)
        const float dv0 = (((a0.x * pb.x) + (a0.y * pb.y)) + (a0.z * pb.z)) + pb.w;
        const float dv1 = (((a0.w * pb.x) + (a1.x * pb.y)) + (a1.y * pb.z)) + pb.w;
        const float dv2 = (((a1.z * pb.x) + (a1.w * pb.y)) + (a8 * pb.z)) + pb.w;
        const float du0 = (((Bv[0] * pa.x) + (Bv[1] * pa.y)) + (Bv[2] * pa.z)) + pa.w;
        const float du1 = (((Bv[3] * pa.x) + (Bv[4] * pa.y)) + (Bv[5] * pa.z)) + pa.w;
        const float du2 = (((Bv[6] * pa.x) + (Bv[7] * pa.y)) + (Bv[8] * pa.z)) + pa.w;
        const float mnv = fminf(fminf(dv0, dv1), dv2), mxv = fmaxf(fmaxf(dv0, dv1), dv2);
        const float mnu = fminf(fminf(du0, du1), du2), mxu = fmaxf(fmaxf(du0, du1), du2);
        const bool ssv = (mnv >= EPS_SNAP) || (mxv <= -EPS_SNAP);
        const bool ssu = (mnu >= EPS_SNAP) || (mxu <= -EPS_SNAP);
        const int i = R + r, j = C + tx;
        const bool surv = !ssv && !ssu && (i != j);
        Sres[r][tx] = (i == j) ? 1.0f : 0.0f;  // survivors overwritten in phase 2
        // wave-aggregated enqueue
        const unsigned long long m = __ballot(surv);
        int wb = 0;
        if (lane == 0) {
            const int wcnt = __popcll(m);
            if (wcnt) wb = atomicAdd(&s_cnt, wcnt);
        }
        wb = __shfl(wb, 0);
        if (surv) {
            const int pos = wb + __popcll(m & ((1ull << lane) - 1ull));
            qbuf[pos] = (unsigned short)((r << 5) | tx);
        }
    }
    __syncthreads();

    // ---- phase 2: full interval test on survivors only ----
    const int total = s_cnt;
    for (int q = t; q < total; q += 256) {
        const int e = qbuf[q];
        const int r = e >> 5, c = e & 31;

        const float4 pa = Apl[r];
        const float4 pq = Bpl[c];
        const float nax = pa.x, nay = pa.y, naz = pa.z, da = pa.w;
        const float nbx = pq.x, nby = pq.y, nbz = pq.z, db = pq.w;

        // snapped distances (reference order + snap); vert arrays die here,
        // before the divide section, to keep VGPR pressure under the 64 cap.
        float dv[3], du[3];
        {
            const float4 a0 = *(const float4*)&Asf[r * 12];
            const float4 a1 = *(const float4*)&Asf[r * 12 + 4];
            const float a8 = Asf[r * 12 + 8];
            dv[0] = snapz((((a0.x * nbx) + (a0.y * nby)) + (a0.z * nbz)) + db);
            dv[1] = snapz((((a0.w * nbx) + (a1.x * nby)) + (a1.y * nbz)) + db);
            dv[2] = snapz((((a1.z * nbx) + (a1.w * nby)) + (a8 * nbz)) + db);
            const float4 b0 = *(const float4*)&Bsf[c * 12];
            const float4 b1 = *(const float4*)&Bsf[c * 12 + 4];
            const float b8 = Bsf[c * 12 + 8];
            du[0] = snapz((((b0.x * nax) + (b0.y * nay)) + (b0.z * naz)) + da);
            du[1] = snapz((((b0.w * nax) + (b1.x * nay)) + (b1.y * naz)) + da);
            du[2] = snapz((((b1.z * nax) + (b1.w * nay)) + (b8 * naz)) + da);
        }

        // plane-plane line direction, dominant axis (first-occurrence argmax)
        const float Dx = nay * nbz - naz * nby;
        const float Dy = naz * nbx - nax * nbz;
        const float Dz = nax * nby - nay * nbx;
        const float m0 = fabsf(Dx), m1 = fabsf(Dy), m2 = fabsf(Dz);
        int axm = 0;
        float mm = m0;
        if (m1 > mm) { axm = 1; mm = m1; }
        if (m2 > mm) { axm = 2; }

        // projections: indexed LDS reads (bitwise-identical to the selects)
        float pv[3], pu[3];
#pragma unroll
        for (int v = 0; v < 3; ++v) {
            pv[v] = Asf[r * 12 + 3 * v + axm];
            pu[v] = Bsf[c * 12 + 3 * v + axm];
        }

        float t0v, t1v, t0u, t1u;
        tri_interval(pv, dv, t0v, t1v);
        tri_interval(pu, du, t0u, t1u);

        const bool overlap = fmaxf(t0v, t0u) <= fminf(t1v, t1u);
        Sres[r][c] = overlap ? 1.0f : 0.0f;  // queued => ~ssv & ~ssu already
    }
    __syncthreads();

    // ---- write out tile (+ mirror), coalesced float4 ----
    {
        const int row = t >> 3;          // 0..31
        const int c4 = (t & 7) * 4;      // 0,4,...,28
        float4 v;
        v.x = Sres[row][c4 + 0]; v.y = Sres[row][c4 + 1];
        v.z = Sres[row][c4 + 2]; v.w = Sres[row][c4 + 3];
        *(float4*)&out[(size_t)(R + row) * n + C + c4] = v;
        if (tr != tc) {
            float4 w;
            w.x = Sres[c4 + 0][row]; w.y = Sres[c4 + 1][row];
            w.z = Sres[c4 + 2][row]; w.w = Sres[c4 + 3][row];
            *(float4*)&out[(size_t)(C + row) * n + R + c4] = w;
        }
    }
}

extern "C" void kernel_launch(void* const* d_in, const int* in_sizes, int n_in,
                              void* d_out, int out_size, void* d_ws, size_t ws_size,
                              hipStream_t stream) {
    const float* tri = (const float*)d_in[0];
    float* out = (float*)d_out;
    const int n = in_sizes[0] / 9;  // 2048

    const int nt = n / TS;                   // 64
    const int nblocks = nt * (nt + 1) / 2;   // 2080 triu tiles
    dim3 block(TS, 8);
    tile_kernel<<<nblocks, block, 0, stream>>>(tri, out, n);
}